// Round 2
// baseline (264.287 us; speedup 1.0000x reference)
//
#include <hip/hip_runtime.h>

// Output layout (float32, concatenated flat in reference return order):
//   [0]                image        64*3*416*416 = 33,226,752
//   [IMG_ELEMS]        targets@13   64*13*13*25  =    270,400
//   [.. + 270400]      targets@26   64*26*26*25  =  1,081,600
//   [.. + 1352000]     targets@52   64*52*52*25  =  4,326,400
#define IMG_ELEMS (64 * 3 * 416 * 416)
#define CELLS_PER_IMG (13*13 + 26*26 + 52*52)   // 3549
#define BASE13 0
#define BASE26 (64 * 169 * 25)                  // 270400
#define BASE52 (BASE26 + 64 * 676 * 25)         // 1352000

__global__ __launch_bounds__(256) void assign_kernel(
    const float* __restrict__ bboxes,  // [64, 32, 4] pixel xywh (center)
    const int*   __restrict__ labels,  // [64, 32]
    float* __restrict__ out)           // d_out + IMG_ELEMS
{
    const int b   = blockIdx.x;
    const int tid = threadIdx.x;

    __shared__ float sbox[32][4];
    __shared__ int   slab[32];
    if (tid < 128) ((float*)sbox)[tid] = bboxes[b * 128 + tid];
    if (tid < 32)  slab[tid] = labels[b * 32 + tid];
    __syncthreads();

    int c = blockIdx.y * blockDim.x + tid;
    if (c >= CELLS_PER_IMG) return;

    int S, idx, base, scale_id;
    if (c < 169)      { S = 13; idx = c;       base = BASE13; scale_id = 0; }
    else if (c < 845) { S = 26; idx = c - 169; base = BASE26; scale_id = 1; }
    else              { S = 52; idx = c - 845; base = BASE52; scale_id = 2; }

    const int i = idx % S;        // x index (scan dim 0; second spatial dim of output)
    const int j = idx / S;        // y index (scan dim 1; first spatial dim of output)
    const float stride = 416.0f / (float)S;   // 32, 16, 8 — exact
    const float inv    = 1.0f / stride;       // power of 2 — exact
    const float fi = (float)i, fj = (float)j;
    const float ci = (fi + 0.5f) * stride;    // pixel center, x
    const float cj = (fj + 0.5f) * stride;    // pixel center, y

    float reg0 = 0.f, reg1 = 0.f, reg2 = 0.f, reg3 = 0.f, reg4 = 0.f;
    unsigned clsmask = 0u;

    for (int n = 0; n < 32; ++n) {
        const float cx = sbox[n][0], cy = sbox[n][1];
        const float bw = sbox[n][2], bh = sbox[n][3];

        const float pos0 = floorf(cx * inv), pos1 = floorf(cy * inv);
        const float bp0  = floorf(0.5f * bw * inv), bp1 = floorf(0.5f * bh * inv);

        const bool region = (fi >= pos0 - bp0) && (fi < pos0 + bp0) &&
                            (fj >= pos1 - bp1) && (fj < pos1 + bp1);
        if (!region) continue;

        // cls[label] := 1 wherever region (independent of band)
        clsmask |= 1u << slab[n];

        const float hw = floorf(0.5f * bw), hh = floorf(0.5f * bh);
        const float L  = ci - (cx - hw);
        const float R  = (cx + hw) - ci;
        const float T  = cj - (cy - hh);
        const float Bo = (cy + hh) - cj;
        const float maxLR = fmaxf(L, R),  minLR = fminf(L, R);
        const float maxTB = fmaxf(T, Bo), minTB = fminf(T, Bo);
        const float m = fmaxf(maxLR, maxTB);

        const bool band = (scale_id == 0) ? (m > 256.0f)
                        : (scale_id == 1) ? (m > 64.0f && m <= 256.0f)
                        :                   (m <= 64.0f);
        if (!band) continue;

        // sequential tie-break: write if untouched or new m < stored channel-max
        const float regmax = fmaxf(fmaxf(fmaxf(reg0, reg1), fmaxf(reg2, reg3)), reg4);
        if (regmax == 0.0f || m < regmax) {
            const float cent = sqrtf((minLR * minTB) / (maxLR * maxTB));
            reg0 = fmaxf(L  * inv, 0.0f);
            reg1 = fmaxf(T  * inv, 0.0f);
            reg2 = fmaxf(R  * inv, 0.0f);
            reg3 = fmaxf(Bo * inv, 0.0f);
            reg4 = fmaxf(cent,     0.0f);
        }
    }

    // out[b, j, i, ch] — ch fastest; ch<20 one-hot cls, ch 20..24 = L,T,R,B (stride
    // units) + centerness.
    float* o = out + base + (((size_t)b * S + j) * S + i) * 25;
    #pragma unroll
    for (int ch = 0; ch < 20; ++ch)
        o[ch] = ((clsmask >> ch) & 1u) ? 1.0f : 0.0f;
    o[20] = reg0; o[21] = reg1; o[22] = reg2; o[23] = reg3; o[24] = reg4;
}

extern "C" void kernel_launch(void* const* d_in, const int* in_sizes, int n_in,
                              void* d_out, int out_size, void* d_ws, size_t ws_size,
                              hipStream_t stream) {
    const float* image  = (const float*)d_in[0];  // [64,3,416,416]
    const float* bboxes = (const float*)d_in[1];  // [64,32,4]
    const int*   labels = (const int*)  d_in[2];  // [64,32]
    float* out = (float*)d_out;

    // 1) image passthrough via runtime D2D copy (graph-legal; may use SDMA path)
    hipMemcpyAsync(out, image, (size_t)IMG_ELEMS * sizeof(float),
                   hipMemcpyDeviceToDevice, stream);

    // 2) target assignment: one thread per cell, sequential 32-box scan in registers
    dim3 grid(64, (CELLS_PER_IMG + 255) / 256);  // (64, 14)
    assign_kernel<<<grid, dim3(256), 0, stream>>>(bboxes, labels, out + IMG_ELEMS);
}

// Round 4
// 248.999 us; speedup vs baseline: 1.0614x; 1.0614x over previous
//
#include <hip/hip_runtime.h>

// Output layout (float32, concatenated flat in reference return order):
//   [0]                image        64*3*416*416 = 33,226,752
//   [IMG_ELEMS]        targets@13   64*13*13*25  =    270,400
//   [.. + 270400]      targets@26   64*26*26*25  =  1,081,600
//   [.. + 1352000]     targets@52   64*52*52*25  =  4,326,400
#define IMG_ELEMS (64 * 3 * 416 * 416)
#define CELLS_PER_IMG (13*13 + 26*26 + 52*52)   // 3549
#define BASE13 0
#define BASE26 (64 * 169 * 25)                  // 270400
#define BASE52 (BASE26 + 64 * 676 * 25)         // 1352000

// Fused grid: blocks [0, ASSIGN_BLOCKS) do target assignment; the rest copy the
// image as 16B vectors (4 per thread). Assign blocks go first so they overlap.
#define ASSIGN_CHUNKS 14                        // ceil(3549/256)
#define ASSIGN_BLOCKS (64 * ASSIGN_CHUNKS)      // 896
#define N4 (IMG_ELEMS / 4)                      // 8,306,688 16B-vectors
#define COPY_BLOCKS (N4 / 1024)                 // 8112 (exact: 256 thr × 4 vec)

typedef float v4f __attribute__((ext_vector_type(4)));  // native vector: ok for
                                                        // __builtin_nontemporal_*

__global__ __launch_bounds__(256) void fused_kernel(
    const v4f* __restrict__ img4,      // image as 16B vectors
    const float* __restrict__ bboxes,  // [64, 32, 4] pixel xywh (center)
    const int*   __restrict__ labels,  // [64, 32]
    float* __restrict__ out)           // d_out base
{
    const int tid = threadIdx.x;

    if (blockIdx.x >= ASSIGN_BLOCKS) {
        // ---- image passthrough: 4 × 16B per thread, nontemporal (pure stream) ----
        v4f* dst4 = (v4f*)out;
        const int cb = blockIdx.x - ASSIGN_BLOCKS;
        const int base = cb * 1024 + tid;
        #pragma unroll
        for (int k = 0; k < 4; ++k) {
            const int idx = base + k * 256;
            v4f v = __builtin_nontemporal_load(&img4[idx]);
            __builtin_nontemporal_store(v, &dst4[idx]);
        }
        return;
    }

    // ---- target assignment: one thread per cell, 32-box sequential scan ----
    const int b     = blockIdx.x / ASSIGN_CHUNKS;
    const int chunk = blockIdx.x % ASSIGN_CHUNKS;

    __shared__ float sbox[32][4];
    __shared__ int   slab[32];
    if (tid < 128) ((float*)sbox)[tid] = bboxes[b * 128 + tid];
    if (tid < 32)  slab[tid] = labels[b * 32 + tid];
    __syncthreads();

    const int c = chunk * 256 + tid;
    if (c >= CELLS_PER_IMG) return;

    int S, idx, base, scale_id;
    if (c < 169)      { S = 13; idx = c;       base = BASE13; scale_id = 0; }
    else if (c < 845) { S = 26; idx = c - 169; base = BASE26; scale_id = 1; }
    else              { S = 52; idx = c - 845; base = BASE52; scale_id = 2; }

    const int i = idx % S;        // x index (scan dim 0; second spatial dim of output)
    const int j = idx / S;        // y index (scan dim 1; first spatial dim of output)
    const float stride = 416.0f / (float)S;   // 32, 16, 8 — exact
    const float inv    = 1.0f / stride;       // power of 2 — exact
    const float fi = (float)i, fj = (float)j;
    const float ci = (fi + 0.5f) * stride;    // pixel center, x
    const float cj = (fj + 0.5f) * stride;    // pixel center, y

    float reg0 = 0.f, reg1 = 0.f, reg2 = 0.f, reg3 = 0.f, reg4 = 0.f;
    unsigned clsmask = 0u;

    for (int n = 0; n < 32; ++n) {
        const float cx = sbox[n][0], cy = sbox[n][1];
        const float bw = sbox[n][2], bh = sbox[n][3];

        const float pos0 = floorf(cx * inv), pos1 = floorf(cy * inv);
        const float bp0  = floorf(0.5f * bw * inv), bp1 = floorf(0.5f * bh * inv);

        const bool region = (fi >= pos0 - bp0) && (fi < pos0 + bp0) &&
                            (fj >= pos1 - bp1) && (fj < pos1 + bp1);
        if (!region) continue;

        // cls[label] := 1 wherever region (independent of band)
        clsmask |= 1u << slab[n];

        const float hw = floorf(0.5f * bw), hh = floorf(0.5f * bh);
        const float L  = ci - (cx - hw);
        const float R  = (cx + hw) - ci;
        const float T  = cj - (cy - hh);
        const float Bo = (cy + hh) - cj;
        const float maxLR = fmaxf(L, R),  minLR = fminf(L, R);
        const float maxTB = fmaxf(T, Bo), minTB = fminf(T, Bo);
        const float m = fmaxf(maxLR, maxTB);

        const bool band = (scale_id == 0) ? (m > 256.0f)
                        : (scale_id == 1) ? (m > 64.0f && m <= 256.0f)
                        :                   (m <= 64.0f);
        if (!band) continue;

        // sequential tie-break: write if untouched or new m < stored channel-max
        const float regmax = fmaxf(fmaxf(fmaxf(reg0, reg1), fmaxf(reg2, reg3)), reg4);
        if (regmax == 0.0f || m < regmax) {
            const float cent = sqrtf((minLR * minTB) / (maxLR * maxTB));
            reg0 = fmaxf(L  * inv, 0.0f);
            reg1 = fmaxf(T  * inv, 0.0f);
            reg2 = fmaxf(R  * inv, 0.0f);
            reg3 = fmaxf(Bo * inv, 0.0f);
            reg4 = fmaxf(cent,     0.0f);
        }
    }

    // out[b, j, i, ch] — ch fastest; ch<20 one-hot cls, ch 20..24 = L,T,R,B (stride
    // units) + centerness.
    float* o = out + IMG_ELEMS + base + (((size_t)b * S + j) * S + i) * 25;
    #pragma unroll
    for (int ch = 0; ch < 20; ++ch)
        o[ch] = ((clsmask >> ch) & 1u) ? 1.0f : 0.0f;
    o[20] = reg0; o[21] = reg1; o[22] = reg2; o[23] = reg3; o[24] = reg4;
}

extern "C" void kernel_launch(void* const* d_in, const int* in_sizes, int n_in,
                              void* d_out, int out_size, void* d_ws, size_t ws_size,
                              hipStream_t stream) {
    const float* image  = (const float*)d_in[0];  // [64,3,416,416]
    const float* bboxes = (const float*)d_in[1];  // [64,32,4]
    const int*   labels = (const int*)  d_in[2];  // [64,32]
    float* out = (float*)d_out;

    fused_kernel<<<dim3(ASSIGN_BLOCKS + COPY_BLOCKS), dim3(256), 0, stream>>>(
        (const v4f*)image, bboxes, labels, out);
}